// Round 4
// baseline (104.074 us; speedup 1.0000x reference)
//
#include <hip/hip_runtime.h>
#include <stdint.h>

// W4 group-quantized linear, v3: register-direct B, frag-major A, no atomics.
//
// Key ideas:
//  * One qweight int32 = 8 consecutive K nibbles = exactly one MFMA B-fragment
//    (16x16x32 bf16: lane holds k = quad*8 + j). B goes global->reg->MFMA,
//    never touching LDS. Unpack = 7 VALU/int32 via (q>>s & 0x000F000F)|0x43004300
//    (biased bf16: 0x4300|n == 128+n exactly), with k-perm sigma=[0,4,1,5,2,6,3,7]
//    inside each 8-block. Legal because MFMA dots A/B positionally per lane;
//    A is stored with the same permutation.
//  * Biased-nibble algebra (per group g): x.W = s*[sum x*(128+nib)] - s*(128+z)*[sum x]
//    with row-sums of the ROUNDED bf16 x precomputed (bias cancels exactly).
//  * cvt kernel emits A in MFMA-frag-major order: flat[(ks*4+i)*64+lane] = 16B frag,
//    so gemm staging is a contiguous 32KB block copy (conflict-free) and frag
//    reads are lane*16 sequential b128.
//  * SPLITK=8 via plain partial stores + reduce kernel (no atomicAdd).
//
// gemm: grid (86,8), 128 thr (2 waves, each M64 x N64), K=512/block in 2 halves
// of 256 (one 32KB A stage each), 4 quant groups folded per block.

#define IN 4096
#define OUT 11008
#define BATCH 64
#define SPLITK 8
#define KSPL 512
#define BN 128
#define GRID_N 86

typedef __attribute__((ext_vector_type(8))) __bf16 bf16x8;
typedef __attribute__((ext_vector_type(4))) float f32x4;

static __device__ __forceinline__ ushort f2bf(float f) {
  uint32_t u = __float_as_uint(f);
  u += 0x7fff + ((u >> 16) & 1); // RNE
  return (ushort)(u >> 16);
}
static __device__ __forceinline__ float bf2f(ushort h) {
  return __uint_as_float(((uint32_t)h) << 16);
}

// x[64][4096] f32 -> xbf in A-frag-major order with kperm [0,4,1,5,2,6,3,7],
// plus xsum[g][m] = sum over group of rounded-bf16 x (shfl-reduce + atomic).
// grid 128 (one block per 32-wide K slab), 256 thr (4 waves = 4 m-frags).
__global__ void cvt_frag_kernel(const float* __restrict__ x,
                                ushort* __restrict__ xbf,
                                float* __restrict__ xsum) {
  const int ks = blockIdx.x;          // 0..127
  const int i = threadIdx.x >> 6;     // m-frag 0..3
  const int lane = threadIdx.x & 63;
  const int mlane = lane & 15, quad = lane >> 4;
  const int m = 16 * i + mlane;
  const int kb = 32 * ks + 8 * quad;
  const float4 lo = *(const float4*)&x[m * IN + kb];
  const float4 hi = *(const float4*)&x[m * IN + kb + 4];
  ushort o[8];
  o[0] = f2bf(lo.x); o[1] = f2bf(hi.x); // k+0, k+4
  o[2] = f2bf(lo.y); o[3] = f2bf(hi.y); // k+1, k+5
  o[4] = f2bf(lo.z); o[5] = f2bf(hi.z); // k+2, k+6
  o[6] = f2bf(lo.w); o[7] = f2bf(hi.w); // k+3, k+7
  const int flat = (ks * 4 + i) * 64 + lane;
  *(uint4*)&xbf[flat * 8] = *(uint4*)o;
  float s = 0.f;
#pragma unroll
  for (int j = 0; j < 8; ++j) s += bf2f(o[j]);
  s += __shfl_xor(s, 16);
  s += __shfl_xor(s, 32); // lanes 0..15 hold per-m sums for this ks-slab
  if (quad == 0) atomicAdd(&xsum[(ks >> 2) * 64 + m], s);
}

__global__ __launch_bounds__(128, 2) void mpq_gemm(
    const ushort* __restrict__ xbf,    // frag-major A
    const int* __restrict__ qweight,   // [512][11008]
    const float* __restrict__ scales,  // [32][11008]
    const float* __restrict__ zeros,   // [32][11008]
    const float* __restrict__ xsum,    // [32][64]
    float* __restrict__ P)             // [8][64][11008] partials
{
  __shared__ uint4 A_lds[2048]; // 32 KB: [ksl 0..7][i 0..3][lane]

  const int n0 = blockIdx.x * BN;
  const int sp = blockIdx.y;
  const int k0 = sp * KSPL;
  const int tid = threadIdx.x;
  const int lane = tid & 63;
  const int w = tid >> 6;               // wave 0/1 -> N half
  const int mlane = lane & 15, quad = lane >> 4;
  const int ncol = n0 + 64 * w + mlane; // col base (j adds 16j)

  f32x4 macc[4][4] = {};

  const uint4* gA = (const uint4*)xbf + (size_t)(k0 / 32) * 256;

  for (int h = 0; h < 2; ++h) {
    __syncthreads(); // previous half's A reads complete
    const uint4* src = gA + (size_t)h * 8 * 256;
#pragma unroll
    for (int it = 0; it < 16; ++it)
      A_lds[tid + 128 * it] = src[tid + 128 * it];
    __syncthreads();

    const int qrow0 = k0 / 8 + h * 32;
#pragma unroll
    for (int g2 = 0; g2 < 2; ++g2) {
      f32x4 gacc[4][4] = {};
#pragma unroll
      for (int ksl = 0; ksl < 4; ++ksl) {
        const int ks = g2 * 4 + ksl; // 0..7 within half
        // B: one int32 per (lane, j) = one B-frag column slice
        uint32_t q[4];
        const int qrow = qrow0 + ks * 4 + quad;
#pragma unroll
        for (int j = 0; j < 4; ++j)
          q[j] = (uint32_t)qweight[(size_t)qrow * OUT + ncol + 16 * j];
        // A frags from LDS (sequential b128, conflict-free)
        bf16x8 af[4];
#pragma unroll
        for (int i = 0; i < 4; ++i)
          af[i] = *(const bf16x8*)&A_lds[(ks * 4 + i) * 64 + lane];
#pragma unroll
        for (int j = 0; j < 4; ++j) {
          uint32_t p[4];
          p[0] = ( q[j]        & 0x000F000Fu) | 0x43004300u;
          p[1] = ((q[j] >>  4) & 0x000F000Fu) | 0x43004300u;
          p[2] = ((q[j] >>  8) & 0x000F000Fu) | 0x43004300u;
          p[3] = ((q[j] >> 12) & 0x000F000Fu) | 0x43004300u;
          bf16x8 bfr = *(bf16x8*)p;
#pragma unroll
          for (int i = 0; i < 4; ++i)
            gacc[i][j] = __builtin_amdgcn_mfma_f32_16x16x32_bf16(af[i], bfr, gacc[i][j], 0, 0, 0);
        }
      }
      // fold group: macc += s*gacc - s*(128+z)*rowsum
      const int g = (k0 >> 7) + h * 2 + g2;
      float Sv[4][4];
#pragma unroll
      for (int i = 0; i < 4; ++i)
#pragma unroll
        for (int r = 0; r < 4; ++r)
          Sv[i][r] = xsum[g * 64 + 16 * i + 4 * quad + r];
#pragma unroll
      for (int j = 0; j < 4; ++j) {
        const float s = scales[g * OUT + ncol + 16 * j];
        const float z = zeros[g * OUT + ncol + 16 * j];
        const float u = s * (128.0f + z);
#pragma unroll
        for (int i = 0; i < 4; ++i)
#pragma unroll
          for (int r = 0; r < 4; ++r)
            macc[i][j][r] = fmaf(s, gacc[i][j][r], fmaf(-u, Sv[i][r], macc[i][j][r]));
      }
    }
  }

  // plain partial stores (64B-coalesced per quad-row)
  float* Pp = P + (size_t)sp * BATCH * OUT;
#pragma unroll
  for (int i = 0; i < 4; ++i)
#pragma unroll
    for (int r = 0; r < 4; ++r) {
      const int m = 16 * i + 4 * quad + r;
#pragma unroll
      for (int j = 0; j < 4; ++j)
        Pp[(size_t)m * OUT + ncol + 16 * j] = macc[i][j][r];
    }
}

__global__ void reduce_kernel(const float* __restrict__ P, float* __restrict__ out) {
  const int t = blockIdx.x * blockDim.x + threadIdx.x; // 176128 float4-slots
  float4 a = ((const float4*)P)[t];
#pragma unroll
  for (int s = 1; s < SPLITK; ++s) {
    float4 b = ((const float4*)P)[t + (size_t)s * (BATCH * OUT / 4)];
    a.x += b.x; a.y += b.y; a.z += b.z; a.w += b.w;
  }
  ((float4*)out)[t] = a;
}

extern "C" void kernel_launch(void* const* d_in, const int* in_sizes, int n_in,
                              void* d_out, int out_size, void* d_ws, size_t ws_size,
                              hipStream_t stream) {
  const float* x = (const float*)d_in[0];
  const int* qweight = (const int*)d_in[1];
  const float* scales = (const float*)d_in[2];
  const float* zeros = (const float*)d_in[3];
  float* out = (float*)d_out;
  ushort* xbf = (ushort*)d_ws;                      // 512 KB, frag-major
  float* xsum = (float*)((char*)d_ws + (1 << 19));  // 8 KB
  float* P = (float*)((char*)d_ws + (1 << 20));     // 22.5 MB partials

  hipMemsetAsync(xsum, 0, 32 * 64 * sizeof(float), stream);
  cvt_frag_kernel<<<128, 256, 0, stream>>>(x, xbf, xsum);
  mpq_gemm<<<dim3(GRID_N, SPLITK), 128, 0, stream>>>(xbf, qweight, scales, zeros, xsum, P);
  reduce_kernel<<<BATCH * OUT / 4 / 256, 256, 0, stream>>>(P, out);
}

// Round 5
// 95.946 us; speedup vs baseline: 1.0847x; 1.0847x over previous
//
#include <hip/hip_runtime.h>
#include <stdint.h>

// W4 group-quantized linear, v4: occupancy + dispatch-count pass.
//  * Same verified math as v3: biased-nibble MFMA B (bf16 0x4300|n == 128+n),
//    k-perm sigma=[0,4,1,5,2,6,3,7] on both A and B, per-group fold
//    x.W = s*gacc - s*(128+z)*xsum, SPLITK=8 partials + reduce.
//  * gemm now 256-thr blocks (4 waves, wave tile M64xN32): 2752 waves
//    (2.7/SIMD vs 1.35 before) and half the per-wave acc pressure.
//  * cvt: one block per quant group -> exact xsum without atomics; memset
//    dispatch eliminated. 3 dispatches total.

#define IN 4096
#define OUT 11008
#define BATCH 64
#define SPLITK 8
#define KSPL 512
#define BN 128
#define GRID_N 86

typedef __attribute__((ext_vector_type(8))) __bf16 bf16x8;
typedef __attribute__((ext_vector_type(4))) float f32x4;

static __device__ __forceinline__ ushort f2bf(float f) {
  uint32_t u = __float_as_uint(f);
  u += 0x7fff + ((u >> 16) & 1); // RNE
  return (ushort)(u >> 16);
}
static __device__ __forceinline__ float bf2f(ushort h) {
  return __uint_as_float(((uint32_t)h) << 16);
}

// One block per quant group g (k in [128g, 128g+128)).
// Thread t: row m = t>>2, quarter q = t&3 -> 32 consecutive k.
// Emits xbf in A-frag-major order with kperm, and xsum[g][m] (shfl, no atomic).
__global__ void cvt_frag_kernel(const float* __restrict__ x,
                                ushort* __restrict__ xbf,
                                float* __restrict__ xsum) {
  const int g = blockIdx.x;
  const int t = threadIdx.x;
  const int m = t >> 2;
  const int q = t & 3;
  const int ks = 4 * g + q;        // 32-wide k slab
  const int kb = 32 * ks;

  float v[32];
  ushort vb[32];
  float s = 0.f;
#pragma unroll
  for (int c4 = 0; c4 < 8; ++c4) {
    float4 f = *(const float4*)&x[m * IN + kb + 4 * c4];
    v[4 * c4 + 0] = f.x; v[4 * c4 + 1] = f.y; v[4 * c4 + 2] = f.z; v[4 * c4 + 3] = f.w;
  }
#pragma unroll
  for (int c = 0; c < 32; ++c) {
    vb[c] = f2bf(v[c]);
    s += bf2f(vb[c]);
  }
  // frag-major stores: for quad qd, positions j hold k = kb + 8*qd + sigma(j),
  // sigma = [0,4,1,5,2,6,3,7]
  const int i = m >> 4, mlane = m & 15;
#pragma unroll
  for (int qd = 0; qd < 4; ++qd) {
    ushort o[8];
    o[0] = vb[8 * qd + 0]; o[1] = vb[8 * qd + 4];
    o[2] = vb[8 * qd + 1]; o[3] = vb[8 * qd + 5];
    o[4] = vb[8 * qd + 2]; o[5] = vb[8 * qd + 6];
    o[6] = vb[8 * qd + 3]; o[7] = vb[8 * qd + 7];
    const int flat = (ks * 4 + i) * 64 + qd * 16 + mlane;
    *(uint4*)&xbf[flat * 8] = *(uint4*)o;
  }
  // combine the 4 quarters of each row (consecutive lanes)
  s += __shfl_xor(s, 1);
  s += __shfl_xor(s, 2);
  if (q == 0) xsum[g * 64 + m] = s;
}

__global__ __launch_bounds__(256, 3) void mpq_gemm(
    const ushort* __restrict__ xbf,    // frag-major A
    const int* __restrict__ qweight,   // [512][11008]
    const float* __restrict__ scales,  // [32][11008]
    const float* __restrict__ zeros,   // [32][11008]
    const float* __restrict__ xsum,    // [32][64]
    float* __restrict__ P)             // [8][64][11008] partials
{
  __shared__ uint4 A_lds[2048]; // 32 KB: [ksl 0..7][i 0..3][lane]

  const int n0 = blockIdx.x * BN;
  const int sp = blockIdx.y;
  const int k0 = sp * KSPL;
  const int tid = threadIdx.x;
  const int lane = tid & 63;
  const int w = tid >> 6;               // wave 0..3 -> N quarter
  const int mlane = lane & 15, quad = lane >> 4;
  const int ncol = n0 + 32 * w + mlane; // col base (j adds 16j)

  f32x4 macc[4][2] = {};

  const uint4* gA = (const uint4*)xbf + (size_t)(k0 / 32) * 256;

  for (int h = 0; h < 2; ++h) {
    __syncthreads(); // previous half's A reads complete
    const uint4* src = gA + (size_t)h * 8 * 256;
#pragma unroll
    for (int it = 0; it < 8; ++it)
      A_lds[tid + 256 * it] = src[tid + 256 * it];
    __syncthreads();

    const int qrow0 = k0 / 8 + h * 32;
#pragma unroll
    for (int g2 = 0; g2 < 2; ++g2) {
      f32x4 gacc[4][2] = {};
#pragma unroll
      for (int ksl = 0; ksl < 4; ++ksl) {
        const int ks = g2 * 4 + ksl; // slab 0..7 within half
        uint32_t q[2];
        const int qrow = qrow0 + ks * 4 + quad;
#pragma unroll
        for (int j = 0; j < 2; ++j)
          q[j] = (uint32_t)qweight[(size_t)qrow * OUT + ncol + 16 * j];
        bf16x8 af[4];
#pragma unroll
        for (int i = 0; i < 4; ++i)
          af[i] = *(const bf16x8*)&A_lds[(ks * 4 + i) * 64 + lane];
#pragma unroll
        for (int j = 0; j < 2; ++j) {
          uint32_t p[4];
          p[0] = ( q[j]        & 0x000F000Fu) | 0x43004300u;
          p[1] = ((q[j] >>  4) & 0x000F000Fu) | 0x43004300u;
          p[2] = ((q[j] >>  8) & 0x000F000Fu) | 0x43004300u;
          p[3] = ((q[j] >> 12) & 0x000F000Fu) | 0x43004300u;
          bf16x8 bfr = *(bf16x8*)p;
#pragma unroll
          for (int i = 0; i < 4; ++i)
            gacc[i][j] = __builtin_amdgcn_mfma_f32_16x16x32_bf16(af[i], bfr, gacc[i][j], 0, 0, 0);
        }
      }
      // fold group: macc += s*gacc - s*(128+z)*rowsum
      const int g = (k0 >> 7) + h * 2 + g2;
      float Sv[4][4];
#pragma unroll
      for (int i = 0; i < 4; ++i)
#pragma unroll
        for (int r = 0; r < 4; ++r)
          Sv[i][r] = xsum[g * 64 + 16 * i + 4 * quad + r];
#pragma unroll
      for (int j = 0; j < 2; ++j) {
        const float s = scales[g * OUT + ncol + 16 * j];
        const float z = zeros[g * OUT + ncol + 16 * j];
        const float u = s * (128.0f + z);
#pragma unroll
        for (int i = 0; i < 4; ++i)
#pragma unroll
          for (int r = 0; r < 4; ++r)
            macc[i][j][r] = fmaf(s, gacc[i][j][r], fmaf(-u, Sv[i][r], macc[i][j][r]));
      }
    }
  }

  // plain partial stores (64B-coalesced per quad-row)
  float* Pp = P + (size_t)sp * BATCH * OUT;
#pragma unroll
  for (int i = 0; i < 4; ++i)
#pragma unroll
    for (int r = 0; r < 4; ++r) {
      const int m = 16 * i + 4 * quad + r;
#pragma unroll
      for (int j = 0; j < 2; ++j)
        Pp[(size_t)m * OUT + ncol + 16 * j] = macc[i][j][r];
    }
}

__global__ void reduce_kernel(const float* __restrict__ P, float* __restrict__ out) {
  const int t = blockIdx.x * blockDim.x + threadIdx.x; // 176128 float4-slots
  float4 a = ((const float4*)P)[t];
#pragma unroll
  for (int s = 1; s < SPLITK; ++s) {
    float4 b = ((const float4*)P)[t + (size_t)s * (BATCH * OUT / 4)];
    a.x += b.x; a.y += b.y; a.z += b.z; a.w += b.w;
  }
  ((float4*)out)[t] = a;
}

extern "C" void kernel_launch(void* const* d_in, const int* in_sizes, int n_in,
                              void* d_out, int out_size, void* d_ws, size_t ws_size,
                              hipStream_t stream) {
  const float* x = (const float*)d_in[0];
  const int* qweight = (const int*)d_in[1];
  const float* scales = (const float*)d_in[2];
  const float* zeros = (const float*)d_in[3];
  float* out = (float*)d_out;
  ushort* xbf = (ushort*)d_ws;                      // 512 KB, frag-major
  float* xsum = (float*)((char*)d_ws + (1 << 19));  // 8 KB
  float* P = (float*)((char*)d_ws + (1 << 20));     // 22.5 MB partials

  cvt_frag_kernel<<<32, 256, 0, stream>>>(x, xbf, xsum);
  mpq_gemm<<<dim3(GRID_N, SPLITK), 256, 0, stream>>>(xbf, qweight, scales, zeros, xsum, P);
  reduce_kernel<<<BATCH * OUT / 4 / 256, 256, 0, stream>>>(P, out);
}